// Round 17
// baseline (8013.285 us; speedup 1.0000x reference)
//
#include <hip/hip_runtime.h>
#include <hip/hip_bf16.h>
#include <math.h>

#define SEQL 2048
#define EDIM 256
#define HID 256
#define G4 1024
#define HCAT 512
#define TT 11
#define START_TAG 9
#define STOP_TAG 10
#define NEGV -10000.0f
#define ALPHA_LR 0.2f
#define VCH 64
#define VCS 32
#define NU 32      // units per LSTM block (8 blocks/direction)
#define HIDX(u) ((((u) >> 5) * 36) + ((u) & 31))   // padded hbuf index (36 floats/chunk)

__device__ __forceinline__ float sigf(float x) { return 1.0f / (1.0f + __expf(-x)); }
__device__ __forceinline__ float tanhfast(float x) { return 2.0f / (1.0f + __expf(-2.0f * x)) - 1.0f; }
__device__ __forceinline__ unsigned int bfp(float f) {
    union { float f; unsigned int u; } c; c.f = f;
    return (c.u + 0x7FFFu + ((c.u >> 16) & 1u)) >> 16;   // RNE bf16 (hi16)
}
__device__ __forceinline__ float bflo(unsigned int u) { return __uint_as_float(u << 16); }
__device__ __forceinline__ float bfhi(unsigned int u) { return __uint_as_float(u & 0xFFFF0000u); }

// ---------------- embedding gather ----------------
__global__ void embed_k(const int* __restrict__ sent, const float* __restrict__ emb,
                        float* __restrict__ x) {
    int idx = blockIdx.x * 256 + threadIdx.x;
    int t = idx >> 8, e = idx & 255;
    x[idx] = emb[(size_t)sent[t] * EDIM + e];
}

// ---------------- GEMM: C[M,N] = A[M,K] * B[N,K]^T + bias ----------------
__global__ __launch_bounds__(256) void gemm_nt(const float* __restrict__ A,
                                               const float* __restrict__ B,
                                               const float* __restrict__ bias,
                                               float* __restrict__ C,
                                               int M, int N, int K) {
    __shared__ float As[16][68];
    __shared__ float Bs[16][68];
    int tid = threadIdx.x;
    int tx = tid & 15, ty = tid >> 4;
    int m0 = blockIdx.y * 64, n0 = blockIdx.x * 64;
    int lr = tid >> 2;
    int lc = (tid & 3) * 4;
    float acc[4][4] = {};
    for (int k0 = 0; k0 < K; k0 += 16) {
        float4 av = *(const float4*)(A + (size_t)(m0 + lr) * K + k0 + lc);
        float4 bv = make_float4(0.f, 0.f, 0.f, 0.f);
        if (n0 + lr < N) bv = *(const float4*)(B + (size_t)(n0 + lr) * K + k0 + lc);
        As[lc + 0][lr] = av.x; As[lc + 1][lr] = av.y; As[lc + 2][lr] = av.z; As[lc + 3][lr] = av.w;
        Bs[lc + 0][lr] = bv.x; Bs[lc + 1][lr] = bv.y; Bs[lc + 2][lr] = bv.z; Bs[lc + 3][lr] = bv.w;
        __syncthreads();
#pragma unroll
        for (int kk = 0; kk < 16; ++kk) {
            float4 a4 = *(const float4*)&As[kk][ty * 4];
            float4 b4 = *(const float4*)&Bs[kk][tx * 4];
            float aa[4] = {a4.x, a4.y, a4.z, a4.w};
            float bb[4] = {b4.x, b4.y, b4.z, b4.w};
#pragma unroll
            for (int i = 0; i < 4; ++i)
#pragma unroll
                for (int j = 0; j < 4; ++j) acc[i][j] += aa[i] * bb[j];
        }
        __syncthreads();
    }
#pragma unroll
    for (int i = 0; i < 4; ++i) {
        int m = m0 + ty * 4 + i;
#pragma unroll
        for (int j = 0; j < 4; ++j) {
            int n = n0 + tx * 4 + j;
            if (n < N) {
                float v = acc[i][j];
                if (bias) v += bias[n];
                C[(size_t)m * N + n] = v;
            }
        }
    }
}

// ---------------- K-split GEMM partials: Cpart[kz] = A[:,kz-slice] * B[kz-slice,:] ----
__global__ __launch_bounds__(256) void gemm_nn_ks(const float* __restrict__ A,
                                                  const float* __restrict__ B,
                                                  float* __restrict__ Cpart,
                                                  int M, int N, int K4) {
    __shared__ float As[16][68];
    __shared__ float Bs[16][68];
    int tid = threadIdx.x;
    int tx = tid & 15, ty = tid >> 4;
    int m0 = blockIdx.y * 64, n0 = blockIdx.x * 64;
    int kz = blockIdx.z;
    int K = (int)gridDim.z * K4;
    int kbeg = kz * K4, kend = kbeg + K4;
    int lr = tid >> 2;
    int lc = (tid & 3) * 4;
    int br = tid >> 4;
    int bc = (tid & 15) * 4;
    float acc[4][4] = {};
    for (int k0 = kbeg; k0 < kend; k0 += 16) {
        float4 av = *(const float4*)(A + (size_t)(m0 + lr) * K + k0 + lc);
        float4 bv = *(const float4*)(B + (size_t)(k0 + br) * N + n0 + bc);
        As[lc + 0][lr] = av.x; As[lc + 1][lr] = av.y; As[lc + 2][lr] = av.z; As[lc + 3][lr] = av.w;
        *(float4*)&Bs[br][bc] = bv;
        __syncthreads();
#pragma unroll
        for (int kk = 0; kk < 16; ++kk) {
            float4 a4 = *(const float4*)&As[kk][ty * 4];
            float4 b4 = *(const float4*)&Bs[kk][tx * 4];
            float aa[4] = {a4.x, a4.y, a4.z, a4.w};
            float bb[4] = {b4.x, b4.y, b4.z, b4.w};
#pragma unroll
            for (int i = 0; i < 4; ++i)
#pragma unroll
                for (int j = 0; j < 4; ++j) acc[i][j] += aa[i] * bb[j];
        }
        __syncthreads();
    }
    float* Cz = Cpart + (size_t)kz * M * N;
#pragma unroll
    for (int i = 0; i < 4; ++i) {
        int m = m0 + ty * 4 + i;
#pragma unroll
        for (int j = 0; j < 4; ++j) {
            int n = n0 + tx * 4 + j;
            Cz[(size_t)m * N + n] = acc[i][j];
        }
    }
}

// ---------------- finishers ----------------
__global__ void attn_fin(const float* __restrict__ Cp, const float* __restrict__ Zr,
                         float* __restrict__ C, int MN, int N) {
    int idx = blockIdx.x * 256 + threadIdx.x;
    float v = Cp[idx] + Cp[MN + idx] + Cp[2 * MN + idx] + Cp[3 * MN + idx];
    v /= Zr[idx / N];
    C[idx] = v > 0.f ? v : (__expf(v) - 1.f);
}

__global__ void sum4_fin(const float* __restrict__ Cp, float* __restrict__ C, int MN) {
    int idx = blockIdx.x * 256 + threadIdx.x;
    C[idx] = Cp[idx] + Cp[MN + idx] + Cp[2 * MN + idx] + Cp[3 * MN + idx];
}

// ---------------- BiLSTM recurrent scan: 8 blocks/dir x 512 thr, pure-atomic exchange
// Round-16 protocol (timed-best 6508us) with HALVED sync participants: block owns 32
// units (128 gate rows), so each direction has 8 blocks -> 7 partners (was 15).
// Dot: thread (rp=tid>>3 in 0..63, k8=tid&7); 64 MACs/thread; 3x shfl_xor reduce over
// the 8-lane k-group -> zred[128]. hbuf padded 36 floats/chunk (bank-conflict-free).
// Exchange: publisher = wave 0 lanes 0..31 (even lanes store 16x 64-bit packed tagged
// pairs, agent-scope atomic only); pollers = waves 1..2 (threads 64..175, one 64-bit
// pair each of the 112 partner pairs) -- disjoint from publisher wave (deadlock-free).
// Word = (bf16(h)<<16 | steptag); pair halves written by ONE store. Parity double-
// buffer; ABA-safe by value dependence; pub memset per launch; per-layer tag bases.
__global__ __launch_bounds__(512) void lstm_lds(const float* __restrict__ xin_f,
                                                const float* __restrict__ xin_b,
                                                const float* __restrict__ whh_f,
                                                const float* __restrict__ whh_b,
                                                const float* __restrict__ hc,
                                                float* __restrict__ out,
                                                unsigned int* pubu, int tagbase) {
    int blk = blockIdx.x;            // 0..15
    int dir = blk >> 3;
    int b = blk & 7;                 // 0..7
    const float* xin = dir ? xin_b : xin_f;
    const float* whh = dir ? whh_b : whh_f;

    int tid = threadIdx.x;

    __shared__ uint4 W4[4096];                    // 64KB bf16 weights
    __shared__ __align__(16) float hbuf[288];     // 8 chunks x 36 floats (padded)
    __shared__ float zred[128];                   // reduced z per gate row

    // ---- one-time weight staging, packed for wave-linear consumption ----
    for (int idx = tid; idx < 4096; idx += 512) {
        int wave = idx >> 9;          // consuming wave 0..7
        int i = (idx >> 6) & 7;       // read index 0..7
        int l = idx & 63;             // lane
        int towner = wave * 64 + l;
        int rp = towner >> 3;         // row-pair 0..63
        int k8 = towner & 7;          // k-chunk 0..7
        int rloc = 2 * rp + (i >> 2); // row 0..127
        int ii = i & 3;
        int g = rloc >> 5, j = rloc & 31;
        const float* wr = whh + (size_t)(g * HID + b * NU + j) * HID + k8 * 32 + ii * 8;
        uint4 v;
        v.x = bfp(wr[0]) | (bfp(wr[1]) << 16);
        v.y = bfp(wr[2]) | (bfp(wr[3]) << 16);
        v.z = bfp(wr[4]) | (bfp(wr[5]) << 16);
        v.w = bfp(wr[6]) | (bfp(wr[7]) << 16);
        W4[wave * 512 + i * 64 + l] = v;
    }

    if (tid < 256) hbuf[HIDX(tid)] = hc[dir * 512 + tid];
    float c = 0.f;
    float xq0 = 0.f, xq1 = 0.f, xq2 = 0.f, xq3 = 0.f;
    if (tid < 32) {
        c = hc[dir * 512 + 256 + b * NU + tid];
        int t0 = dir ? (SEQL - 1) : 0;
        const float* xr = xin + (size_t)t0 * G4 + b * NU + tid;
        xq0 = xr[0]; xq1 = xr[256]; xq2 = xr[512]; xq3 = xr[768];
    }
    __syncthreads();

    int rp = tid >> 3;                 // row-pair 0..63
    int k8 = tid & 7;                  // k-chunk 0..7 (adjacent lanes)
    int wbase = (tid >> 6) * 512 + (tid & 63);

    // poller mapping: tid 64..175 -> one of 112 partner unit-pairs
    int ppair = tid - 64;
    int upair = (ppair < b * 16) ? ppair : ppair + 16;  // skip own block's 16 pairs

    for (int s = 0; s < SEQL; ++s) {
        // ---- dot phase: all 512 threads ----
        const float4* hp = (const float4*)(hbuf + k8 * 36);
        float acc0 = 0.f, acc1 = 0.f;
#pragma unroll
        for (int i = 0; i < 4; ++i) {
            uint4 w0 = W4[wbase + i * 64];
            uint4 w1 = W4[wbase + (i + 4) * 64];
            float4 hA = hp[i * 2];
            float4 hB = hp[i * 2 + 1];
            acc0 += bflo(w0.x) * hA.x + bfhi(w0.x) * hA.y + bflo(w0.y) * hA.z + bfhi(w0.y) * hA.w
                  + bflo(w0.z) * hB.x + bfhi(w0.z) * hB.y + bflo(w0.w) * hB.z + bfhi(w0.w) * hB.w;
            acc1 += bflo(w1.x) * hA.x + bfhi(w1.x) * hA.y + bflo(w1.y) * hA.z + bfhi(w1.y) * hA.w
                  + bflo(w1.z) * hB.x + bfhi(w1.z) * hB.y + bflo(w1.w) * hB.z + bfhi(w1.w) * hB.w;
        }
        acc0 += __shfl_xor(acc0, 1, 64); acc1 += __shfl_xor(acc1, 1, 64);
        acc0 += __shfl_xor(acc0, 2, 64); acc1 += __shfl_xor(acc1, 2, 64);
        acc0 += __shfl_xor(acc0, 4, 64); acc1 += __shfl_xor(acc1, 4, 64);
        if (k8 == 0) {
            zred[2 * rp] = acc0;
            zred[2 * rp + 1] = acc1;
        }
        __syncthreads();

        int t = dir ? (SEQL - 1 - s) : s;
        unsigned int etag = (unsigned int)(tagbase + s + 1) & 0xFFFFu;
        unsigned int* slot = pubu + (((s + 1) & 1) * 2 + dir) * 256;

        if (tid < 32) {
            // ---- gate phase + 64-bit packed publish (wave 0) ----
            float zi = xq0 + zred[tid];
            float zf = xq1 + zred[32 + tid];
            float zg = xq2 + zred[64 + tid];
            float zo = xq3 + zred[96 + tid];
            float ig = sigf(zi), fg = sigf(zf), gt = tanhfast(zg), og = sigf(zo);
            c = fg * c + ig * gt;
            float hn = og * tanhfast(c);
            int u = b * NU + tid;
            hbuf[HIDX(u)] = hn;
            unsigned int word = (bfp(hn) << 16) | etag;
            unsigned int wnext = __shfl_down(word, 1, 64);
            if ((tid & 1) == 0) {
                unsigned long long w64 = (unsigned long long)word |
                                         ((unsigned long long)wnext << 32);
                __hip_atomic_store((unsigned long long*)&slot[u], w64,
                                   __ATOMIC_RELAXED, __HIP_MEMORY_SCOPE_AGENT);
            }
            out[(size_t)t * HCAT + dir * HID + u] = hn;
            // prefetch next x
            if (s + 1 < SEQL) {
                int tn = dir ? (SEQL - 2 - s) : (s + 1);
                const float* xr = xin + (size_t)tn * G4 + b * NU + tid;
                xq0 = xr[0]; xq1 = xr[256]; xq2 = xr[512]; xq3 = xr[768];
            }
        } else if (tid >= 64 && tid < 176 && s + 1 < SEQL) {
            // ---- poll phase: waves 1..2, one 64-bit atomic load per thread ----
            unsigned long long v;
            for (;;) {
                v = __hip_atomic_load((unsigned long long*)&slot[upair * 2],
                                      __ATOMIC_RELAXED, __HIP_MEMORY_SCOPE_AGENT);
                if ((unsigned int)(v & 0xFFFFu) == etag &&
                    (unsigned int)((v >> 32) & 0xFFFFu) == etag) break;
            }
            hbuf[HIDX(upair * 2)]     = bfhi((unsigned int)v);
            hbuf[HIDX(upair * 2 + 1)] = bfhi((unsigned int)(v >> 32));
        }
        __syncthreads();
    }
}

// ---------------- GAT helpers ----------------
__global__ void gat_scores(const float* __restrict__ Wh, const float* __restrict__ a,
                           float* __restrict__ s1, float* __restrict__ s2) {
    int i = blockIdx.x;
    int lane = threadIdx.x;  // 64
    const float* rowp = Wh + (size_t)i * HCAT;
    float p1 = 0.f, p2 = 0.f;
    for (int k = lane; k < HCAT; k += 64) {
        float w = rowp[k];
        p1 += w * a[k];
        p2 += w * a[HCAT + k];
    }
    for (int off = 32; off; off >>= 1) {
        p1 += __shfl_down(p1, off, 64);
        p2 += __shfl_down(p2, off, 64);
    }
    if (lane == 0) { s1[i] = p1; s2[i] = p2; }
}

__global__ void reduce_max_k(const float* __restrict__ s2, float* __restrict__ outv) {
    __shared__ float red[256];
    int tid = threadIdx.x;
    float m = -INFINITY;
    for (int k = tid; k < SEQL; k += 256) m = fmaxf(m, s2[k]);
    red[tid] = m;
    __syncthreads();
    for (int off = 128; off; off >>= 1) {
        if (tid < off) red[tid] = fmaxf(red[tid], red[tid + off]);
        __syncthreads();
    }
    if (tid == 0) outv[0] = red[0];
}

__global__ void gat_p(const float* __restrict__ s1, const float* __restrict__ s2,
                      const float* __restrict__ s2m, float* __restrict__ P,
                      float* __restrict__ Z) {
    int i = blockIdx.x;
    int tid = threadIdx.x;  // 256
    float base = s1[i];
    float m = base + s2m[0];
    m = m > 0.f ? m : ALPHA_LR * m;  // leaky_relu monotonic -> exact row max
    float zs = 0.f;
    for (int jj = tid; jj < SEQL; jj += 256) {
        float e = base + s2[jj];
        e = e > 0.f ? e : ALPHA_LR * e;
        float p = __expf(e - m);
        P[(size_t)i * SEQL + jj] = p;
        zs += p;
    }
    __shared__ float red[256];
    red[tid] = zs;
    __syncthreads();
    for (int off = 128; off; off >>= 1) {
        if (tid < off) red[tid] += red[tid + off];
        __syncthreads();
    }
    if (tid == 0) Z[i] = red[0];
}

// ---------------- Viterbi (max-plus parallel scan) ----------------
__global__ void vit_chunkA(const float* __restrict__ feats, const float* __restrict__ trans,
                           float* __restrict__ chunkA) {
    int c = blockIdx.x;
    int tid = threadIdx.x;  // 128
    __shared__ float Acur[121], tr[121];
    if (tid < 121) tr[tid] = trans[tid];
    __syncthreads();
    int n = tid / 11, p = tid % 11;
    int t0 = c * VCS;
    if (tid < 121) Acur[tid] = tr[tid] + feats[t0 * TT + n];
    __syncthreads();
    for (int t = t0 + 1; t < t0 + VCS; ++t) {
        float v = -INFINITY;
        if (tid < 121) {
            float ft = feats[t * TT + n];
#pragma unroll
            for (int k = 0; k < 11; ++k) v = fmaxf(v, tr[n * 11 + k] + Acur[k * 11 + p]);
            v += ft;
        }
        __syncthreads();
        if (tid < 121) Acur[tid] = v;
        __syncthreads();
    }
    if (tid < 121) chunkA[c * 121 + tid] = Acur[tid];
}

__global__ void vit_prefix(const float* __restrict__ chunkA, float* __restrict__ fvstart) {
    int tid = threadIdx.x;  // 128
    __shared__ float fv[11];
    if (tid < 11) fv[tid] = (tid == START_TAG) ? 0.f : NEGV;
    __syncthreads();
    if (tid < 11) fvstart[tid] = fv[tid];
    for (int c = 0; c < VCH; ++c) {
        float v = -INFINITY;
        if (tid < 11) {
            for (int p = 0; p < 11; ++p) v = fmaxf(v, chunkA[c * 121 + tid * 11 + p] + fv[p]);
        }
        __syncthreads();
        if (tid < 11) { fv[tid] = v; fvstart[(c + 1) * TT + tid] = v; }
        __syncthreads();
    }
}

__global__ void vit_chunkC(const float* __restrict__ feats, const float* __restrict__ trans,
                           const float* __restrict__ fvstart, int* __restrict__ bp,
                           float* __restrict__ fvfinal) {
    int c = blockIdx.x;
    int tid = threadIdx.x;  // 128
    __shared__ float fv[11], tr[121], sc[121], mx[11];
    if (tid < 121) tr[tid] = trans[tid];
    if (tid < 11) fv[tid] = fvstart[c * TT + tid];
    __syncthreads();
    int t0 = c * VCS;
    for (int t = t0; t < t0 + VCS; ++t) {
        if (tid < 121) sc[tid] = fv[tid % 11] + tr[tid];
        __syncthreads();
        if (tid < 11) {
            float best = -INFINITY;
            int bi = 0;
            for (int k = 0; k < 11; ++k) {
                float v = sc[tid * 11 + k];
                if (v > best) { best = v; bi = k; }
            }
            bp[t * TT + tid] = bi;
            mx[tid] = best + feats[t * TT + tid];
        }
        __syncthreads();
        if (tid < 11) fv[tid] = mx[tid];
        __syncthreads();
    }
    if (c == VCH - 1 && tid < 11) fvfinal[tid] = fv[tid];
}

__global__ __launch_bounds__(1024) void vit_back(const int* __restrict__ bp,
                                                 const float* __restrict__ fvfinal,
                                                 const float* __restrict__ trans,
                                                 float* __restrict__ outp) {
    __shared__ unsigned char bufA[SEQL * TT];
    __shared__ unsigned char bufB[SEQL * TT];
    __shared__ int bestIdx;
    int tid = threadIdx.x;
    for (int idx = tid; idx < SEQL * TT; idx += 1024) {
        int t = idx / TT, n = idx - t * TT;
        bufA[idx] = (t < SEQL - 1) ? (unsigned char)bp[(t + 1) * TT + n] : (unsigned char)n;
    }
    __syncthreads();
    unsigned char* a = bufA;
    unsigned char* b = bufB;
    for (int len = 1; len < SEQL - 1; len <<= 1) {
        for (int idx = tid; idx < SEQL * TT; idx += 1024) {
            int t = idx / TT, n = idx - t * TT;
            int m = (t + len <= SEQL - 1) ? (int)a[(t + len) * TT + n] : n;
            b[t * TT + n] = a[t * TT + m];
        }
        __syncthreads();
        unsigned char* tmp = a; a = b; b = tmp;
        __syncthreads();
    }
    if (tid == 0) {
        float bs = -INFINITY;
        int bi = 0;
        for (int p = 0; p < 11; ++p) {
            float v = fvfinal[p] + trans[STOP_TAG * 11 + p];
            if (v > bs) { bs = v; bi = p; }
        }
        outp[0] = bs;
        bestIdx = bi;
    }
    __syncthreads();
    int best = bestIdx;
    for (int t = tid; t < SEQL; t += 1024) outp[1 + t] = (float)a[t * TT + best];
}

// ---------------- host launcher ----------------
extern "C" void kernel_launch(void* const* d_in, const int* in_sizes, int n_in,
                              void* d_out, int out_size, void* d_ws, size_t ws_size,
                              hipStream_t stream) {
    const int* sent = (const int*)d_in[0];
    const float* emb = (const float*)d_in[1];
    const float* w1f = (const float*)d_in[2];
    const float* u1f = (const float*)d_in[3];
    const float* b1f = (const float*)d_in[4];
    const float* w1b = (const float*)d_in[5];
    const float* u1b = (const float*)d_in[6];
    const float* b1b = (const float*)d_in[7];
    const float* hc1 = (const float*)d_in[8];
    const float* g1W = (const float*)d_in[9];
    const float* g1a = (const float*)d_in[10];
    const float* g2W = (const float*)d_in[11];
    const float* g2a = (const float*)d_in[12];
    const float* w2f = (const float*)d_in[13];
    const float* u2f = (const float*)d_in[14];
    const float* b2f = (const float*)d_in[15];
    const float* w2b = (const float*)d_in[16];
    const float* u2b = (const float*)d_in[17];
    const float* b2b = (const float*)d_in[18];
    const float* hc2 = (const float*)d_in[19];
    const float* wtag = (const float*)d_in[20];
    const float* btag = (const float*)d_in[21];
    const float* trans = (const float*)d_in[22];

    float* ws = (float*)d_ws;
    float* x = ws;                      // 524288
    float* R1 = x + 524288;             // 4194304 floats (xin_f+xin_b | P)
    float* xin_f = R1;
    float* xin_b = R1 + 2097152;
    float* P = R1;
    float* h1cat = R1 + 4194304;        // 1048576 (h1cat | g2)
    float* Wh = h1cat + 1048576;        // 1048576
    float* g1 = Wh + 1048576;           // 1048576 (g1 | h2cat)
    float* s1 = g1 + 1048576;           // 2048
    float* s2 = s1 + 2048;              // 2048
    float* Zr = s2 + 2048;              // 2048
    float* s2m = Zr + 2048;             // 16
    unsigned int* pub = (unsigned int*)(s2m + 16);  // 1024 u32 (8B-aligned)
    float* feats = (float*)(pub + 1024);            // 22528
    float* chA = feats + 22528;         // 7744
    float* fvst = chA + 7744;           // 720
    float* fvfin = fvst + 720;          // 16
    int* bp = (int*)(fvfin + 16);       // 22528 ints
    float* Cpart = (float*)(bp + 22528); // 4x1048576 floats (16MB)

    hipMemsetAsync(pub, 0, 1024 * sizeof(unsigned int), stream);

    embed_k<<<SEQL, 256, 0, stream>>>(sent, emb, x);

    // BiLSTM 1 input projections
    gemm_nt<<<dim3(16, 32), 256, 0, stream>>>(x, w1f, b1f, xin_f, SEQL, G4, EDIM);
    gemm_nt<<<dim3(16, 32), 256, 0, stream>>>(x, w1b, b1b, xin_b, SEQL, G4, EDIM);
    lstm_lds<<<16, 512, 0, stream>>>(xin_f, xin_b, u1f, u1b, hc1, h1cat, pub, 0);

    // GAT 1 (both GEMMs K-split x4 for occupancy)
    gemm_nn_ks<<<dim3(8, 32, 4), 256, 0, stream>>>(h1cat, g1W, Cpart, SEQL, HCAT, HCAT / 4);
    sum4_fin<<<4096, 256, 0, stream>>>(Cpart, Wh, SEQL * HCAT);
    gat_scores<<<SEQL, 64, 0, stream>>>(Wh, g1a, s1, s2);
    reduce_max_k<<<1, 256, 0, stream>>>(s2, s2m);
    gat_p<<<SEQL, 256, 0, stream>>>(s1, s2, s2m, P, Zr);
    gemm_nn_ks<<<dim3(8, 32, 4), 256, 0, stream>>>(P, Wh, Cpart, SEQL, HCAT, SEQL / 4);
    attn_fin<<<4096, 256, 0, stream>>>(Cpart, Zr, g1, SEQL * HCAT, HCAT);

    // GAT 2
    gemm_nn_ks<<<dim3(8, 32, 4), 256, 0, stream>>>(g1, g2W, Cpart, SEQL, HCAT, HCAT / 4);
    sum4_fin<<<4096, 256, 0, stream>>>(Cpart, Wh, SEQL * HCAT);
    gat_scores<<<SEQL, 64, 0, stream>>>(Wh, g2a, s1, s2);
    reduce_max_k<<<1, 256, 0, stream>>>(s2, s2m);
    gat_p<<<SEQL, 256, 0, stream>>>(s1, s2, s2m, P, Zr);
    float* g2v = h1cat;  // reuse
    gemm_nn_ks<<<dim3(8, 32, 4), 256, 0, stream>>>(P, Wh, Cpart, SEQL, HCAT, SEQL / 4);
    attn_fin<<<4096, 256, 0, stream>>>(Cpart, Zr, g2v, SEQL * HCAT, HCAT);

    // BiLSTM 2
    gemm_nt<<<dim3(16, 32), 256, 0, stream>>>(g2v, w2f, b2f, xin_f, SEQL, G4, HCAT);
    gemm_nt<<<dim3(16, 32), 256, 0, stream>>>(g2v, w2b, b2b, xin_b, SEQL, G4, HCAT);
    float* h2cat = g1;  // reuse
    lstm_lds<<<16, 512, 0, stream>>>(xin_f, xin_b, u2f, u2b, hc2, h2cat, pub, 2048);

    // tag projection + Viterbi
    gemm_nt<<<dim3(1, 32), 256, 0, stream>>>(h2cat, wtag, btag, feats, SEQL, TT, HCAT);
    vit_chunkA<<<VCH, 128, 0, stream>>>(feats, trans, chA);
    vit_prefix<<<1, 128, 0, stream>>>(chA, fvst);
    vit_chunkC<<<VCH, 128, 0, stream>>>(feats, trans, fvst, bp, fvfin);
    vit_back<<<1, 1024, 0, stream>>>(bp, fvfin, trans, (float*)d_out);
}

// Round 18
// 7984.425 us; speedup vs baseline: 1.0036x; 1.0036x over previous
//
#include <hip/hip_runtime.h>
#include <hip/hip_bf16.h>
#include <math.h>

#define SEQL 2048
#define EDIM 256
#define HID 256
#define G4 1024
#define HCAT 512
#define TT 11
#define START_TAG 9
#define STOP_TAG 10
#define NEGV -10000.0f
#define ALPHA_LR 0.2f
#define VCH 64
#define VCS 32
#define NU 16      // units per LSTM block
#define HIDX(u) ((((u) >> 5) * 36) + ((u) & 31))   // padded hbuf index (36 floats/chunk)

__device__ __forceinline__ float sigf(float x) { return 1.0f / (1.0f + __expf(-x)); }
__device__ __forceinline__ float tanhfast(float x) { return 2.0f / (1.0f + __expf(-2.0f * x)) - 1.0f; }
__device__ __forceinline__ unsigned int bfp(float f) {
    union { float f; unsigned int u; } c; c.f = f;
    return (c.u + 0x7FFFu + ((c.u >> 16) & 1u)) >> 16;   // RNE bf16 (hi16)
}
__device__ __forceinline__ float bflo(unsigned int u) { return __uint_as_float(u << 16); }
__device__ __forceinline__ float bfhi(unsigned int u) { return __uint_as_float(u & 0xFFFF0000u); }

// ---------------- embedding gather ----------------
__global__ void embed_k(const int* __restrict__ sent, const float* __restrict__ emb,
                        float* __restrict__ x) {
    int idx = blockIdx.x * 256 + threadIdx.x;
    int t = idx >> 8, e = idx & 255;
    x[idx] = emb[(size_t)sent[t] * EDIM + e];
}

// ---------------- GEMM: C[M,N] = A[M,K] * B[N,K]^T + bias (full-K, used for feats) ---
__global__ __launch_bounds__(256) void gemm_nt(const float* __restrict__ A,
                                               const float* __restrict__ B,
                                               const float* __restrict__ bias,
                                               float* __restrict__ C,
                                               int M, int N, int K) {
    __shared__ float As[16][68];
    __shared__ float Bs[16][68];
    int tid = threadIdx.x;
    int tx = tid & 15, ty = tid >> 4;
    int m0 = blockIdx.y * 64, n0 = blockIdx.x * 64;
    int lr = tid >> 2;
    int lc = (tid & 3) * 4;
    float acc[4][4] = {};
    for (int k0 = 0; k0 < K; k0 += 16) {
        float4 av = *(const float4*)(A + (size_t)(m0 + lr) * K + k0 + lc);
        float4 bv = make_float4(0.f, 0.f, 0.f, 0.f);
        if (n0 + lr < N) bv = *(const float4*)(B + (size_t)(n0 + lr) * K + k0 + lc);
        As[lc + 0][lr] = av.x; As[lc + 1][lr] = av.y; As[lc + 2][lr] = av.z; As[lc + 3][lr] = av.w;
        Bs[lc + 0][lr] = bv.x; Bs[lc + 1][lr] = bv.y; Bs[lc + 2][lr] = bv.z; Bs[lc + 3][lr] = bv.w;
        __syncthreads();
#pragma unroll
        for (int kk = 0; kk < 16; ++kk) {
            float4 a4 = *(const float4*)&As[kk][ty * 4];
            float4 b4 = *(const float4*)&Bs[kk][tx * 4];
            float aa[4] = {a4.x, a4.y, a4.z, a4.w};
            float bb[4] = {b4.x, b4.y, b4.z, b4.w};
#pragma unroll
            for (int i = 0; i < 4; ++i)
#pragma unroll
                for (int j = 0; j < 4; ++j) acc[i][j] += aa[i] * bb[j];
        }
        __syncthreads();
    }
#pragma unroll
    for (int i = 0; i < 4; ++i) {
        int m = m0 + ty * 4 + i;
#pragma unroll
        for (int j = 0; j < 4; ++j) {
            int n = n0 + tx * 4 + j;
            if (n < N) {
                float v = acc[i][j];
                if (bias) v += bias[n];
                C[(size_t)m * N + n] = v;
            }
        }
    }
}

// ---------------- K-split GEMM-NT partials: Cpart[kz] = A[:,kz] * B[:,kz]^T ----------
__global__ __launch_bounds__(256) void gemm_nt_ks(const float* __restrict__ A,
                                                  const float* __restrict__ B,
                                                  float* __restrict__ Cpart,
                                                  int M, int N, int Ks) {
    __shared__ float As[16][68];
    __shared__ float Bs[16][68];
    int tid = threadIdx.x;
    int tx = tid & 15, ty = tid >> 4;
    int m0 = blockIdx.y * 64, n0 = blockIdx.x * 64;
    int kz = blockIdx.z;
    int K = (int)gridDim.z * Ks;
    int kbeg = kz * Ks, kend = kbeg + Ks;
    int lr = tid >> 2;
    int lc = (tid & 3) * 4;
    float acc[4][4] = {};
    for (int k0 = kbeg; k0 < kend; k0 += 16) {
        float4 av = *(const float4*)(A + (size_t)(m0 + lr) * K + k0 + lc);
        float4 bv = *(const float4*)(B + (size_t)(n0 + lr) * K + k0 + lc);
        As[lc + 0][lr] = av.x; As[lc + 1][lr] = av.y; As[lc + 2][lr] = av.z; As[lc + 3][lr] = av.w;
        Bs[lc + 0][lr] = bv.x; Bs[lc + 1][lr] = bv.y; Bs[lc + 2][lr] = bv.z; Bs[lc + 3][lr] = bv.w;
        __syncthreads();
#pragma unroll
        for (int kk = 0; kk < 16; ++kk) {
            float4 a4 = *(const float4*)&As[kk][ty * 4];
            float4 b4 = *(const float4*)&Bs[kk][tx * 4];
            float aa[4] = {a4.x, a4.y, a4.z, a4.w};
            float bb[4] = {b4.x, b4.y, b4.z, b4.w};
#pragma unroll
            for (int i = 0; i < 4; ++i)
#pragma unroll
                for (int j = 0; j < 4; ++j) acc[i][j] += aa[i] * bb[j];
        }
        __syncthreads();
    }
    float* Cz = Cpart + (size_t)kz * M * N;
#pragma unroll
    for (int i = 0; i < 4; ++i) {
        int m = m0 + ty * 4 + i;
#pragma unroll
        for (int j = 0; j < 4; ++j) {
            int n = n0 + tx * 4 + j;
            Cz[(size_t)m * N + n] = acc[i][j];
        }
    }
}

// ---------------- K-split GEMM-NN partials: Cpart[kz] = A[:,kz-slice] * B[kz-slice,:] -
__global__ __launch_bounds__(256) void gemm_nn_ks(const float* __restrict__ A,
                                                  const float* __restrict__ B,
                                                  float* __restrict__ Cpart,
                                                  int M, int N, int K4) {
    __shared__ float As[16][68];
    __shared__ float Bs[16][68];
    int tid = threadIdx.x;
    int tx = tid & 15, ty = tid >> 4;
    int m0 = blockIdx.y * 64, n0 = blockIdx.x * 64;
    int kz = blockIdx.z;
    int K = (int)gridDim.z * K4;
    int kbeg = kz * K4, kend = kbeg + K4;
    int lr = tid >> 2;
    int lc = (tid & 3) * 4;
    int br = tid >> 4;
    int bc = (tid & 15) * 4;
    float acc[4][4] = {};
    for (int k0 = kbeg; k0 < kend; k0 += 16) {
        float4 av = *(const float4*)(A + (size_t)(m0 + lr) * K + k0 + lc);
        float4 bv = *(const float4*)(B + (size_t)(k0 + br) * N + n0 + bc);
        As[lc + 0][lr] = av.x; As[lc + 1][lr] = av.y; As[lc + 2][lr] = av.z; As[lc + 3][lr] = av.w;
        *(float4*)&Bs[br][bc] = bv;
        __syncthreads();
#pragma unroll
        for (int kk = 0; kk < 16; ++kk) {
            float4 a4 = *(const float4*)&As[kk][ty * 4];
            float4 b4 = *(const float4*)&Bs[kk][tx * 4];
            float aa[4] = {a4.x, a4.y, a4.z, a4.w};
            float bb[4] = {b4.x, b4.y, b4.z, b4.w};
#pragma unroll
            for (int i = 0; i < 4; ++i)
#pragma unroll
                for (int j = 0; j < 4; ++j) acc[i][j] += aa[i] * bb[j];
        }
        __syncthreads();
    }
    float* Cz = Cpart + (size_t)kz * M * N;
#pragma unroll
    for (int i = 0; i < 4; ++i) {
        int m = m0 + ty * 4 + i;
#pragma unroll
        for (int j = 0; j < 4; ++j) {
            int n = n0 + tx * 4 + j;
            Cz[(size_t)m * N + n] = acc[i][j];
        }
    }
}

// ---------------- finishers ----------------
__global__ void attn_fin(const float* __restrict__ Cp, const float* __restrict__ Zr,
                         float* __restrict__ C, int MN, int N) {
    int idx = blockIdx.x * 256 + threadIdx.x;
    float v = Cp[idx] + Cp[MN + idx] + Cp[2 * MN + idx] + Cp[3 * MN + idx];
    v /= Zr[idx / N];
    C[idx] = v > 0.f ? v : (__expf(v) - 1.f);
}

__global__ void sum4_fin(const float* __restrict__ Cp, float* __restrict__ C, int MN) {
    int idx = blockIdx.x * 256 + threadIdx.x;
    C[idx] = Cp[idx] + Cp[MN + idx] + Cp[2 * MN + idx] + Cp[3 * MN + idx];
}

__global__ void sum2_bias_fin(const float* __restrict__ Cp, const float* __restrict__ bias,
                              float* __restrict__ C, int MN, int N) {
    int idx = blockIdx.x * 256 + threadIdx.x;
    C[idx] = Cp[idx] + Cp[MN + idx] + bias[idx & (N - 1)];
}

// ---------------- BiLSTM recurrent scan: ROUND-16 VERBATIM (timed-best 6508us) ------
// Pure-atomic 64-bit packed exchange, placement-independent. Publisher = wave 0 lanes
// 0..15 (even lanes store tagged pairs). Pollers = waves 1..2 ONLY (disjoint from the
// publisher wave -> publisher always progresses). Dot remap (rp=tid>>3, k8=tid&7) +
// 3x shfl_xor in-wave reduce -> zred[64]; hbuf padded 36 floats/chunk.
// Word = (bf16(h)<<16 | steptag); pair written by ONE store. Parity double-buffer;
// ABA-safe by value dependence; pub memset per launch; per-layer tag bases.
__global__ __launch_bounds__(256) void lstm_lds(const float* __restrict__ xin_f,
                                                const float* __restrict__ xin_b,
                                                const float* __restrict__ whh_f,
                                                const float* __restrict__ whh_b,
                                                const float* __restrict__ hc,
                                                float* __restrict__ out,
                                                unsigned int* pubu, int tagbase) {
    int raw = blockIdx.x;
    int lane7 = raw & 7;
    if (lane7 > 1) return;           // 96 dummy blocks exit
    int dir = lane7;
    int b = raw >> 3;                // 0..15
    const float* xin = dir ? xin_b : xin_f;
    const float* whh = dir ? whh_b : whh_f;

    int tid = threadIdx.x;

    __shared__ uint4 W4[2048];                    // 32KB bf16 weights
    __shared__ __align__(16) float hbuf[288];     // 8 chunks x 36 floats (padded)
    __shared__ float zred[64];                    // reduced z per gate row

    // ---- one-time weight staging, packed for wave-linear consumption ----
    for (int idx = tid; idx < 2048; idx += 256) {
        int wave = idx >> 9;
        int i = (idx >> 6) & 7;
        int l = idx & 63;
        int towner = wave * 64 + l;
        int rp = towner >> 3;
        int k8 = towner & 7;
        int rloc = 2 * rp + (i >> 2);
        int ii = i & 3;
        int g = rloc >> 4, j = rloc & 15;
        const float* wr = whh + (size_t)(g * HID + b * NU + j) * HID + k8 * 32 + ii * 8;
        uint4 v;
        v.x = bfp(wr[0]) | (bfp(wr[1]) << 16);
        v.y = bfp(wr[2]) | (bfp(wr[3]) << 16);
        v.z = bfp(wr[4]) | (bfp(wr[5]) << 16);
        v.w = bfp(wr[6]) | (bfp(wr[7]) << 16);
        W4[wave * 512 + i * 64 + l] = v;
    }

    if (tid < 256) hbuf[HIDX(tid)] = hc[dir * 512 + tid];
    float c = 0.f;
    float xq0 = 0.f, xq1 = 0.f, xq2 = 0.f, xq3 = 0.f;
    if (tid < 16) {
        c = hc[dir * 512 + 256 + b * NU + tid];
        int t0 = dir ? (SEQL - 1) : 0;
        const float* xr = xin + (size_t)t0 * G4 + b * NU + tid;
        xq0 = xr[0]; xq1 = xr[256]; xq2 = xr[512]; xq3 = xr[768];
    }
    __syncthreads();

    int rp = tid >> 3;                 // row-pair 0..31
    int k8 = tid & 7;                  // k-chunk 0..7 (adjacent lanes)
    int wbase = (tid >> 6) * 512 + (tid & 63);

    // poller mapping: tid 64..183 -> one of 120 partner unit-pairs
    int ppair = tid - 64;
    int upair = (ppair < b * 8) ? ppair : ppair + 8;

    for (int s = 0; s < SEQL; ++s) {
        // ---- dot phase: all 256 threads ----
        const float4* hp = (const float4*)(hbuf + k8 * 36);
        float acc0 = 0.f, acc1 = 0.f;
#pragma unroll
        for (int i = 0; i < 4; ++i) {
            uint4 w0 = W4[wbase + i * 64];
            uint4 w1 = W4[wbase + (i + 4) * 64];
            float4 hA = hp[i * 2];
            float4 hB = hp[i * 2 + 1];
            acc0 += bflo(w0.x) * hA.x + bfhi(w0.x) * hA.y + bflo(w0.y) * hA.z + bfhi(w0.y) * hA.w
                  + bflo(w0.z) * hB.x + bfhi(w0.z) * hB.y + bflo(w0.w) * hB.z + bfhi(w0.w) * hB.w;
            acc1 += bflo(w1.x) * hA.x + bfhi(w1.x) * hA.y + bflo(w1.y) * hA.z + bfhi(w1.y) * hA.w
                  + bflo(w1.z) * hB.x + bfhi(w1.z) * hB.y + bflo(w1.w) * hB.z + bfhi(w1.w) * hB.w;
        }
        acc0 += __shfl_xor(acc0, 1, 64); acc1 += __shfl_xor(acc1, 1, 64);
        acc0 += __shfl_xor(acc0, 2, 64); acc1 += __shfl_xor(acc1, 2, 64);
        acc0 += __shfl_xor(acc0, 4, 64); acc1 += __shfl_xor(acc1, 4, 64);
        if (k8 == 0) {
            zred[2 * rp] = acc0;
            zred[2 * rp + 1] = acc1;
        }
        __syncthreads();

        int t = dir ? (SEQL - 1 - s) : s;
        unsigned int etag = (unsigned int)(tagbase + s + 1) & 0xFFFFu;
        unsigned int* slot = pubu + (((s + 1) & 1) * 2 + dir) * 256;

        if (tid < 16) {
            // ---- gate phase + 64-bit packed publish (wave 0) ----
            float zi = xq0 + zred[tid];
            float zf = xq1 + zred[16 + tid];
            float zg = xq2 + zred[32 + tid];
            float zo = xq3 + zred[48 + tid];
            float ig = sigf(zi), fg = sigf(zf), gt = tanhfast(zg), og = sigf(zo);
            c = fg * c + ig * gt;
            float hn = og * tanhfast(c);
            int u = b * NU + tid;
            hbuf[HIDX(u)] = hn;
            unsigned int word = (bfp(hn) << 16) | etag;
            unsigned int wnext = __shfl_down(word, 1, 64);
            if ((tid & 1) == 0) {
                unsigned long long w64 = (unsigned long long)word |
                                         ((unsigned long long)wnext << 32);
                __hip_atomic_store((unsigned long long*)&slot[u], w64,
                                   __ATOMIC_RELAXED, __HIP_MEMORY_SCOPE_AGENT);
            }
            out[(size_t)t * HCAT + dir * HID + u] = hn;
            // prefetch next x
            if (s + 1 < SEQL) {
                int tn = dir ? (SEQL - 2 - s) : (s + 1);
                const float* xr = xin + (size_t)tn * G4 + b * NU + tid;
                xq0 = xr[0]; xq1 = xr[256]; xq2 = xr[512]; xq3 = xr[768];
            }
        } else if (tid >= 64 && tid < 184 && s + 1 < SEQL) {
            // ---- poll phase: waves 1..2, one 64-bit atomic load per thread ----
            unsigned long long v;
            for (;;) {
                v = __hip_atomic_load((unsigned long long*)&slot[upair * 2],
                                      __ATOMIC_RELAXED, __HIP_MEMORY_SCOPE_AGENT);
                if ((unsigned int)(v & 0xFFFFu) == etag &&
                    (unsigned int)((v >> 32) & 0xFFFFu) == etag) break;
            }
            hbuf[HIDX(upair * 2)]     = bfhi((unsigned int)v);
            hbuf[HIDX(upair * 2 + 1)] = bfhi((unsigned int)(v >> 32));
        }
        __syncthreads();
    }
}

// ---------------- GAT helpers ----------------
__global__ void gat_scores(const float* __restrict__ Wh, const float* __restrict__ a,
                           float* __restrict__ s1, float* __restrict__ s2) {
    int i = blockIdx.x;
    int lane = threadIdx.x;  // 64
    const float* rowp = Wh + (size_t)i * HCAT;
    float p1 = 0.f, p2 = 0.f;
    for (int k = lane; k < HCAT; k += 64) {
        float w = rowp[k];
        p1 += w * a[k];
        p2 += w * a[HCAT + k];
    }
    for (int off = 32; off; off >>= 1) {
        p1 += __shfl_down(p1, off, 64);
        p2 += __shfl_down(p2, off, 64);
    }
    if (lane == 0) { s1[i] = p1; s2[i] = p2; }
}

__global__ void reduce_max_k(const float* __restrict__ s2, float* __restrict__ outv) {
    __shared__ float red[256];
    int tid = threadIdx.x;
    float m = -INFINITY;
    for (int k = tid; k < SEQL; k += 256) m = fmaxf(m, s2[k]);
    red[tid] = m;
    __syncthreads();
    for (int off = 128; off; off >>= 1) {
        if (tid < off) red[tid] = fmaxf(red[tid], red[tid + off]);
        __syncthreads();
    }
    if (tid == 0) outv[0] = red[0];
}

__global__ void gat_p(const float* __restrict__ s1, const float* __restrict__ s2,
                      const float* __restrict__ s2m, float* __restrict__ P,
                      float* __restrict__ Z) {
    int i = blockIdx.x;
    int tid = threadIdx.x;  // 256
    float base = s1[i];
    float m = base + s2m[0];
    m = m > 0.f ? m : ALPHA_LR * m;  // leaky_relu monotonic -> exact row max
    float zs = 0.f;
    for (int jj = tid; jj < SEQL; jj += 256) {
        float e = base + s2[jj];
        e = e > 0.f ? e : ALPHA_LR * e;
        float p = __expf(e - m);
        P[(size_t)i * SEQL + jj] = p;
        zs += p;
    }
    __shared__ float red[256];
    red[tid] = zs;
    __syncthreads();
    for (int off = 128; off; off >>= 1) {
        if (tid < off) red[tid] += red[tid + off];
        __syncthreads();
    }
    if (tid == 0) Z[i] = red[0];
}

// ---------------- Viterbi (max-plus parallel scan) ----------------
__global__ void vit_chunkA(const float* __restrict__ feats, const float* __restrict__ trans,
                           float* __restrict__ chunkA) {
    int c = blockIdx.x;
    int tid = threadIdx.x;  // 128
    __shared__ float Acur[121], tr[121];
    if (tid < 121) tr[tid] = trans[tid];
    __syncthreads();
    int n = tid / 11, p = tid % 11;
    int t0 = c * VCS;
    if (tid < 121) Acur[tid] = tr[tid] + feats[t0 * TT + n];
    __syncthreads();
    for (int t = t0 + 1; t < t0 + VCS; ++t) {
        float v = -INFINITY;
        if (tid < 121) {
            float ft = feats[t * TT + n];
#pragma unroll
            for (int k = 0; k < 11; ++k) v = fmaxf(v, tr[n * 11 + k] + Acur[k * 11 + p]);
            v += ft;
        }
        __syncthreads();
        if (tid < 121) Acur[tid] = v;
        __syncthreads();
    }
    if (tid < 121) chunkA[c * 121 + tid] = Acur[tid];
}

__global__ void vit_prefix(const float* __restrict__ chunkA, float* __restrict__ fvstart) {
    int tid = threadIdx.x;  // 128
    __shared__ float fv[11];
    if (tid < 11) fv[tid] = (tid == START_TAG) ? 0.f : NEGV;
    __syncthreads();
    if (tid < 11) fvstart[tid] = fv[tid];
    for (int c = 0; c < VCH; ++c) {
        float v = -INFINITY;
        if (tid < 11) {
            for (int p = 0; p < 11; ++p) v = fmaxf(v, chunkA[c * 121 + tid * 11 + p] + fv[p]);
        }
        __syncthreads();
        if (tid < 11) { fv[tid] = v; fvstart[(c + 1) * TT + tid] = v; }
        __syncthreads();
    }
}

__global__ void vit_chunkC(const float* __restrict__ feats, const float* __restrict__ trans,
                           const float* __restrict__ fvstart, int* __restrict__ bp,
                           float* __restrict__ fvfinal) {
    int c = blockIdx.x;
    int tid = threadIdx.x;  // 128
    __shared__ float fv[11], tr[121], sc[121], mx[11];
    if (tid < 121) tr[tid] = trans[tid];
    if (tid < 11) fv[tid] = fvstart[c * TT + tid];
    __syncthreads();
    int t0 = c * VCS;
    for (int t = t0; t < t0 + VCS; ++t) {
        if (tid < 121) sc[tid] = fv[tid % 11] + tr[tid];
        __syncthreads();
        if (tid < 11) {
            float best = -INFINITY;
            int bi = 0;
            for (int k = 0; k < 11; ++k) {
                float v = sc[tid * 11 + k];
                if (v > best) { best = v; bi = k; }
            }
            bp[t * TT + tid] = bi;
            mx[tid] = best + feats[t * TT + tid];
        }
        __syncthreads();
        if (tid < 11) fv[tid] = mx[tid];
        __syncthreads();
    }
    if (c == VCH - 1 && tid < 11) fvfinal[tid] = fv[tid];
}

__global__ __launch_bounds__(1024) void vit_back(const int* __restrict__ bp,
                                                 const float* __restrict__ fvfinal,
                                                 const float* __restrict__ trans,
                                                 float* __restrict__ outp) {
    __shared__ unsigned char bufA[SEQL * TT];
    __shared__ unsigned char bufB[SEQL * TT];
    __shared__ int bestIdx;
    int tid = threadIdx.x;
    for (int idx = tid; idx < SEQL * TT; idx += 1024) {
        int t = idx / TT, n = idx - t * TT;
        bufA[idx] = (t < SEQL - 1) ? (unsigned char)bp[(t + 1) * TT + n] : (unsigned char)n;
    }
    __syncthreads();
    unsigned char* a = bufA;
    unsigned char* b = bufB;
    for (int len = 1; len < SEQL - 1; len <<= 1) {
        for (int idx = tid; idx < SEQL * TT; idx += 1024) {
            int t = idx / TT, n = idx - t * TT;
            int m = (t + len <= SEQL - 1) ? (int)a[(t + len) * TT + n] : n;
            b[t * TT + n] = a[t * TT + m];
        }
        __syncthreads();
        unsigned char* tmp = a; a = b; b = tmp;
        __syncthreads();
    }
    if (tid == 0) {
        float bs = -INFINITY;
        int bi = 0;
        for (int p = 0; p < 11; ++p) {
            float v = fvfinal[p] + trans[STOP_TAG * 11 + p];
            if (v > bs) { bs = v; bi = p; }
        }
        outp[0] = bs;
        bestIdx = bi;
    }
    __syncthreads();
    int best = bestIdx;
    for (int t = tid; t < SEQL; t += 1024) outp[1 + t] = (float)a[t * TT + best];
}

// ---------------- host launcher ----------------
extern "C" void kernel_launch(void* const* d_in, const int* in_sizes, int n_in,
                              void* d_out, int out_size, void* d_ws, size_t ws_size,
                              hipStream_t stream) {
    const int* sent = (const int*)d_in[0];
    const float* emb = (const float*)d_in[1];
    const float* w1f = (const float*)d_in[2];
    const float* u1f = (const float*)d_in[3];
    const float* b1f = (const float*)d_in[4];
    const float* w1b = (const float*)d_in[5];
    const float* u1b = (const float*)d_in[6];
    const float* b1b = (const float*)d_in[7];
    const float* hc1 = (const float*)d_in[8];
    const float* g1W = (const float*)d_in[9];
    const float* g1a = (const float*)d_in[10];
    const float* g2W = (const float*)d_in[11];
    const float* g2a = (const float*)d_in[12];
    const float* w2f = (const float*)d_in[13];
    const float* u2f = (const float*)d_in[14];
    const float* b2f = (const float*)d_in[15];
    const float* w2b = (const float*)d_in[16];
    const float* u2b = (const float*)d_in[17];
    const float* b2b = (const float*)d_in[18];
    const float* hc2 = (const float*)d_in[19];
    const float* wtag = (const float*)d_in[20];
    const float* btag = (const float*)d_in[21];
    const float* trans = (const float*)d_in[22];

    float* ws = (float*)d_ws;
    float* x = ws;                      // 524288
    float* R1 = x + 524288;             // 4194304 floats (xin_f+xin_b | P)
    float* xin_f = R1;
    float* xin_b = R1 + 2097152;
    float* P = R1;
    float* h1cat = R1 + 4194304;        // 1048576 (h1cat | g2)
    float* Wh = h1cat + 1048576;        // 1048576
    float* g1 = Wh + 1048576;           // 1048576 (g1 | h2cat)
    float* s1 = g1 + 1048576;           // 2048
    float* s2 = s1 + 2048;              // 2048
    float* Zr = s2 + 2048;              // 2048
    float* s2m = Zr + 2048;             // 16
    unsigned int* pub = (unsigned int*)(s2m + 16);  // 1024 u32 (8B-aligned)
    float* feats = (float*)(pub + 1024);            // 22528
    float* chA = feats + 22528;         // 7744
    float* fvst = chA + 7744;           // 720
    float* fvfin = fvst + 720;          // 16
    int* bp = (int*)(fvfin + 16);       // 22528 ints
    float* Cpart = (float*)(bp + 22528); // 4x1048576 floats (16MB)

    hipMemsetAsync(pub, 0, 1024 * sizeof(unsigned int), stream);

    embed_k<<<SEQL, 256, 0, stream>>>(sent, emb, x);

    // BiLSTM 1 input projections (K-split x2: 4 blocks/CU)
    gemm_nt_ks<<<dim3(16, 32, 2), 256, 0, stream>>>(x, w1f, Cpart, SEQL, G4, EDIM / 2);
    sum2_bias_fin<<<8192, 256, 0, stream>>>(Cpart, b1f, xin_f, SEQL * G4, G4);
    gemm_nt_ks<<<dim3(16, 32, 2), 256, 0, stream>>>(x, w1b, Cpart, SEQL, G4, EDIM / 2);
    sum2_bias_fin<<<8192, 256, 0, stream>>>(Cpart, b1b, xin_b, SEQL * G4, G4);
    lstm_lds<<<128, 256, 0, stream>>>(xin_f, xin_b, u1f, u1b, hc1, h1cat, pub, 0);

    // GAT 1 (both GEMMs K-split x4 for occupancy)
    gemm_nn_ks<<<dim3(8, 32, 4), 256, 0, stream>>>(h1cat, g1W, Cpart, SEQL, HCAT, HCAT / 4);
    sum4_fin<<<4096, 256, 0, stream>>>(Cpart, Wh, SEQL * HCAT);
    gat_scores<<<SEQL, 64, 0, stream>>>(Wh, g1a, s1, s2);
    reduce_max_k<<<1, 256, 0, stream>>>(s2, s2m);
    gat_p<<<SEQL, 256, 0, stream>>>(s1, s2, s2m, P, Zr);
    gemm_nn_ks<<<dim3(8, 32, 4), 256, 0, stream>>>(P, Wh, Cpart, SEQL, HCAT, SEQL / 4);
    attn_fin<<<4096, 256, 0, stream>>>(Cpart, Zr, g1, SEQL * HCAT, HCAT);

    // GAT 2
    gemm_nn_ks<<<dim3(8, 32, 4), 256, 0, stream>>>(g1, g2W, Cpart, SEQL, HCAT, HCAT / 4);
    sum4_fin<<<4096, 256, 0, stream>>>(Cpart, Wh, SEQL * HCAT);
    gat_scores<<<SEQL, 64, 0, stream>>>(Wh, g2a, s1, s2);
    reduce_max_k<<<1, 256, 0, stream>>>(s2, s2m);
    gat_p<<<SEQL, 256, 0, stream>>>(s1, s2, s2m, P, Zr);
    float* g2v = h1cat;  // reuse
    gemm_nn_ks<<<dim3(8, 32, 4), 256, 0, stream>>>(P, Wh, Cpart, SEQL, HCAT, SEQL / 4);
    attn_fin<<<4096, 256, 0, stream>>>(Cpart, Zr, g2v, SEQL * HCAT, HCAT);

    // BiLSTM 2 input projections (K-split x2)
    gemm_nt_ks<<<dim3(16, 32, 2), 256, 0, stream>>>(g2v, w2f, Cpart, SEQL, G4, HCAT / 2);
    sum2_bias_fin<<<8192, 256, 0, stream>>>(Cpart, b2f, xin_f, SEQL * G4, G4);
    gemm_nt_ks<<<dim3(16, 32, 2), 256, 0, stream>>>(g2v, w2b, Cpart, SEQL, G4, HCAT / 2);
    sum2_bias_fin<<<8192, 256, 0, stream>>>(Cpart, b2b, xin_b, SEQL * G4, G4);
    float* h2cat = g1;  // reuse
    lstm_lds<<<128, 256, 0, stream>>>(xin_f, xin_b, u2f, u2b, hc2, h2cat, pub, 2048);

    // tag projection + Viterbi
    gemm_nt<<<dim3(1, 32), 256, 0, stream>>>(h2cat, wtag, btag, feats, SEQL, TT, HCAT);
    vit_chunkA<<<VCH, 128, 0, stream>>>(feats, trans, chA);
    vit_prefix<<<1, 128, 0, stream>>>(chA, fvst);
    vit_chunkC<<<VCH, 128, 0, stream>>>(feats, trans, fvst, bp, fvfin);
    vit_back<<<1, 1024, 0, stream>>>(bp, fvfin, trans, (float*)d_out);
}

// Round 19
// 6514.716 us; speedup vs baseline: 1.2300x; 1.2256x over previous
//
#include <hip/hip_runtime.h>
#include <hip/hip_bf16.h>
#include <math.h>

#define SEQL 2048
#define EDIM 256
#define HID 256
#define G4 1024
#define HCAT 512
#define TT 11
#define START_TAG 9
#define STOP_TAG 10
#define NEGV -10000.0f
#define ALPHA_LR 0.2f
#define VCH 64
#define VCS 32
#define NU 16      // units per LSTM block
#define HIDX(u) ((((u) >> 5) * 36) + ((u) & 31))   // padded hbuf index (36 floats/chunk)

__device__ __forceinline__ float sigf(float x) { return 1.0f / (1.0f + __expf(-x)); }
__device__ __forceinline__ float tanhfast(float x) { return 2.0f / (1.0f + __expf(-2.0f * x)) - 1.0f; }
__device__ __forceinline__ unsigned int bfp(float f) {
    union { float f; unsigned int u; } c; c.f = f;
    return (c.u + 0x7FFFu + ((c.u >> 16) & 1u)) >> 16;   // RNE bf16 (hi16)
}
__device__ __forceinline__ float bflo(unsigned int u) { return __uint_as_float(u << 16); }
__device__ __forceinline__ float bfhi(unsigned int u) { return __uint_as_float(u & 0xFFFF0000u); }

// ---------------- embedding gather ----------------
__global__ void embed_k(const int* __restrict__ sent, const float* __restrict__ emb,
                        float* __restrict__ x) {
    int idx = blockIdx.x * 256 + threadIdx.x;
    int t = idx >> 8, e = idx & 255;
    x[idx] = emb[(size_t)sent[t] * EDIM + e];
}

// ---------------- GEMM: C[M,N] = A[M,K] * B[N,K]^T + bias ----------------
__global__ __launch_bounds__(256) void gemm_nt(const float* __restrict__ A,
                                               const float* __restrict__ B,
                                               const float* __restrict__ bias,
                                               float* __restrict__ C,
                                               int M, int N, int K) {
    __shared__ float As[16][68];
    __shared__ float Bs[16][68];
    int tid = threadIdx.x;
    int tx = tid & 15, ty = tid >> 4;
    int m0 = blockIdx.y * 64, n0 = blockIdx.x * 64;
    int lr = tid >> 2;
    int lc = (tid & 3) * 4;
    float acc[4][4] = {};
    for (int k0 = 0; k0 < K; k0 += 16) {
        float4 av = *(const float4*)(A + (size_t)(m0 + lr) * K + k0 + lc);
        float4 bv = make_float4(0.f, 0.f, 0.f, 0.f);
        if (n0 + lr < N) bv = *(const float4*)(B + (size_t)(n0 + lr) * K + k0 + lc);
        As[lc + 0][lr] = av.x; As[lc + 1][lr] = av.y; As[lc + 2][lr] = av.z; As[lc + 3][lr] = av.w;
        Bs[lc + 0][lr] = bv.x; Bs[lc + 1][lr] = bv.y; Bs[lc + 2][lr] = bv.z; Bs[lc + 3][lr] = bv.w;
        __syncthreads();
#pragma unroll
        for (int kk = 0; kk < 16; ++kk) {
            float4 a4 = *(const float4*)&As[kk][ty * 4];
            float4 b4 = *(const float4*)&Bs[kk][tx * 4];
            float aa[4] = {a4.x, a4.y, a4.z, a4.w};
            float bb[4] = {b4.x, b4.y, b4.z, b4.w};
#pragma unroll
            for (int i = 0; i < 4; ++i)
#pragma unroll
                for (int j = 0; j < 4; ++j) acc[i][j] += aa[i] * bb[j];
        }
        __syncthreads();
    }
#pragma unroll
    for (int i = 0; i < 4; ++i) {
        int m = m0 + ty * 4 + i;
#pragma unroll
        for (int j = 0; j < 4; ++j) {
            int n = n0 + tx * 4 + j;
            if (n < N) {
                float v = acc[i][j];
                if (bias) v += bias[n];
                C[(size_t)m * N + n] = v;
            }
        }
    }
}

// ---------------- K-split GEMM partials: Cpart[kz] = A[:,kz-slice] * B[kz-slice,:] ----
__global__ __launch_bounds__(256) void gemm_nn_ks(const float* __restrict__ A,
                                                  const float* __restrict__ B,
                                                  float* __restrict__ Cpart,
                                                  int M, int N, int K4) {
    __shared__ float As[16][68];
    __shared__ float Bs[16][68];
    int tid = threadIdx.x;
    int tx = tid & 15, ty = tid >> 4;
    int m0 = blockIdx.y * 64, n0 = blockIdx.x * 64;
    int kz = blockIdx.z;
    int K = (int)gridDim.z * K4;
    int kbeg = kz * K4, kend = kbeg + K4;
    int lr = tid >> 2;
    int lc = (tid & 3) * 4;
    int br = tid >> 4;
    int bc = (tid & 15) * 4;
    float acc[4][4] = {};
    for (int k0 = kbeg; k0 < kend; k0 += 16) {
        float4 av = *(const float4*)(A + (size_t)(m0 + lr) * K + k0 + lc);
        float4 bv = *(const float4*)(B + (size_t)(k0 + br) * N + n0 + bc);
        As[lc + 0][lr] = av.x; As[lc + 1][lr] = av.y; As[lc + 2][lr] = av.z; As[lc + 3][lr] = av.w;
        *(float4*)&Bs[br][bc] = bv;
        __syncthreads();
#pragma unroll
        for (int kk = 0; kk < 16; ++kk) {
            float4 a4 = *(const float4*)&As[kk][ty * 4];
            float4 b4 = *(const float4*)&Bs[kk][tx * 4];
            float aa[4] = {a4.x, a4.y, a4.z, a4.w};
            float bb[4] = {b4.x, b4.y, b4.z, b4.w};
#pragma unroll
            for (int i = 0; i < 4; ++i)
#pragma unroll
                for (int j = 0; j < 4; ++j) acc[i][j] += aa[i] * bb[j];
        }
        __syncthreads();
    }
    float* Cz = Cpart + (size_t)kz * M * N;
#pragma unroll
    for (int i = 0; i < 4; ++i) {
        int m = m0 + ty * 4 + i;
#pragma unroll
        for (int j = 0; j < 4; ++j) {
            int n = n0 + tx * 4 + j;
            Cz[(size_t)m * N + n] = acc[i][j];
        }
    }
}

// ---------------- finishers ----------------
__global__ void attn_fin(const float* __restrict__ Cp, const float* __restrict__ Zr,
                         float* __restrict__ C, int MN, int N) {
    int idx = blockIdx.x * 256 + threadIdx.x;
    float v = Cp[idx] + Cp[MN + idx] + Cp[2 * MN + idx] + Cp[3 * MN + idx];
    v /= Zr[idx / N];
    C[idx] = v > 0.f ? v : (__expf(v) - 1.f);
}

__global__ void sum4_fin(const float* __restrict__ Cp, float* __restrict__ C, int MN) {
    int idx = blockIdx.x * 256 + threadIdx.x;
    C[idx] = Cp[idx] + Cp[MN + idx] + Cp[2 * MN + idx] + Cp[3 * MN + idx];
}

// ---------------- BiLSTM recurrent scan: ROUND-16 VERBATIM (timed-best 6508us) ------
// Pure-atomic 64-bit packed exchange, placement-independent. Publisher = wave 0 lanes
// 0..15 (even lanes store tagged pairs). Pollers = waves 1..2 ONLY (disjoint from the
// publisher wave -> publisher always progresses). Dot remap (rp=tid>>3, k8=tid&7) +
// 3x shfl_xor in-wave reduce -> zred[64]; hbuf padded 36 floats/chunk.
// Word = (bf16(h)<<16 | steptag); pair written by ONE store. Parity double-buffer;
// ABA-safe by value dependence; pub memset per launch; per-layer tag bases.
__global__ __launch_bounds__(256) void lstm_lds(const float* __restrict__ xin_f,
                                                const float* __restrict__ xin_b,
                                                const float* __restrict__ whh_f,
                                                const float* __restrict__ whh_b,
                                                const float* __restrict__ hc,
                                                float* __restrict__ out,
                                                unsigned int* pubu, int tagbase) {
    int raw = blockIdx.x;
    int lane7 = raw & 7;
    if (lane7 > 1) return;           // 96 dummy blocks exit
    int dir = lane7;
    int b = raw >> 3;                // 0..15
    const float* xin = dir ? xin_b : xin_f;
    const float* whh = dir ? whh_b : whh_f;

    int tid = threadIdx.x;

    __shared__ uint4 W4[2048];                    // 32KB bf16 weights
    __shared__ __align__(16) float hbuf[288];     // 8 chunks x 36 floats (padded)
    __shared__ float zred[64];                    // reduced z per gate row

    // ---- one-time weight staging, packed for wave-linear consumption ----
    for (int idx = tid; idx < 2048; idx += 256) {
        int wave = idx >> 9;
        int i = (idx >> 6) & 7;
        int l = idx & 63;
        int towner = wave * 64 + l;
        int rp = towner >> 3;
        int k8 = towner & 7;
        int rloc = 2 * rp + (i >> 2);
        int ii = i & 3;
        int g = rloc >> 4, j = rloc & 15;
        const float* wr = whh + (size_t)(g * HID + b * NU + j) * HID + k8 * 32 + ii * 8;
        uint4 v;
        v.x = bfp(wr[0]) | (bfp(wr[1]) << 16);
        v.y = bfp(wr[2]) | (bfp(wr[3]) << 16);
        v.z = bfp(wr[4]) | (bfp(wr[5]) << 16);
        v.w = bfp(wr[6]) | (bfp(wr[7]) << 16);
        W4[wave * 512 + i * 64 + l] = v;
    }

    if (tid < 256) hbuf[HIDX(tid)] = hc[dir * 512 + tid];
    float c = 0.f;
    float xq0 = 0.f, xq1 = 0.f, xq2 = 0.f, xq3 = 0.f;
    if (tid < 16) {
        c = hc[dir * 512 + 256 + b * NU + tid];
        int t0 = dir ? (SEQL - 1) : 0;
        const float* xr = xin + (size_t)t0 * G4 + b * NU + tid;
        xq0 = xr[0]; xq1 = xr[256]; xq2 = xr[512]; xq3 = xr[768];
    }
    __syncthreads();

    int rp = tid >> 3;                 // row-pair 0..31
    int k8 = tid & 7;                  // k-chunk 0..7 (adjacent lanes)
    int wbase = (tid >> 6) * 512 + (tid & 63);

    // poller mapping: tid 64..183 -> one of 120 partner unit-pairs
    int ppair = tid - 64;
    int upair = (ppair < b * 8) ? ppair : ppair + 8;

    for (int s = 0; s < SEQL; ++s) {
        // ---- dot phase: all 256 threads ----
        const float4* hp = (const float4*)(hbuf + k8 * 36);
        float acc0 = 0.f, acc1 = 0.f;
#pragma unroll
        for (int i = 0; i < 4; ++i) {
            uint4 w0 = W4[wbase + i * 64];
            uint4 w1 = W4[wbase + (i + 4) * 64];
            float4 hA = hp[i * 2];
            float4 hB = hp[i * 2 + 1];
            acc0 += bflo(w0.x) * hA.x + bfhi(w0.x) * hA.y + bflo(w0.y) * hA.z + bfhi(w0.y) * hA.w
                  + bflo(w0.z) * hB.x + bfhi(w0.z) * hB.y + bflo(w0.w) * hB.z + bfhi(w0.w) * hB.w;
            acc1 += bflo(w1.x) * hA.x + bfhi(w1.x) * hA.y + bflo(w1.y) * hA.z + bfhi(w1.y) * hA.w
                  + bflo(w1.z) * hB.x + bfhi(w1.z) * hB.y + bflo(w1.w) * hB.z + bfhi(w1.w) * hB.w;
        }
        acc0 += __shfl_xor(acc0, 1, 64); acc1 += __shfl_xor(acc1, 1, 64);
        acc0 += __shfl_xor(acc0, 2, 64); acc1 += __shfl_xor(acc1, 2, 64);
        acc0 += __shfl_xor(acc0, 4, 64); acc1 += __shfl_xor(acc1, 4, 64);
        if (k8 == 0) {
            zred[2 * rp] = acc0;
            zred[2 * rp + 1] = acc1;
        }
        __syncthreads();

        int t = dir ? (SEQL - 1 - s) : s;
        unsigned int etag = (unsigned int)(tagbase + s + 1) & 0xFFFFu;
        unsigned int* slot = pubu + (((s + 1) & 1) * 2 + dir) * 256;

        if (tid < 16) {
            // ---- gate phase + 64-bit packed publish (wave 0) ----
            float zi = xq0 + zred[tid];
            float zf = xq1 + zred[16 + tid];
            float zg = xq2 + zred[32 + tid];
            float zo = xq3 + zred[48 + tid];
            float ig = sigf(zi), fg = sigf(zf), gt = tanhfast(zg), og = sigf(zo);
            c = fg * c + ig * gt;
            float hn = og * tanhfast(c);
            int u = b * NU + tid;
            hbuf[HIDX(u)] = hn;
            unsigned int word = (bfp(hn) << 16) | etag;
            unsigned int wnext = __shfl_down(word, 1, 64);
            if ((tid & 1) == 0) {
                unsigned long long w64 = (unsigned long long)word |
                                         ((unsigned long long)wnext << 32);
                __hip_atomic_store((unsigned long long*)&slot[u], w64,
                                   __ATOMIC_RELAXED, __HIP_MEMORY_SCOPE_AGENT);
            }
            out[(size_t)t * HCAT + dir * HID + u] = hn;
            // prefetch next x
            if (s + 1 < SEQL) {
                int tn = dir ? (SEQL - 2 - s) : (s + 1);
                const float* xr = xin + (size_t)tn * G4 + b * NU + tid;
                xq0 = xr[0]; xq1 = xr[256]; xq2 = xr[512]; xq3 = xr[768];
            }
        } else if (tid >= 64 && tid < 184 && s + 1 < SEQL) {
            // ---- poll phase: waves 1..2, one 64-bit atomic load per thread ----
            unsigned long long v;
            for (;;) {
                v = __hip_atomic_load((unsigned long long*)&slot[upair * 2],
                                      __ATOMIC_RELAXED, __HIP_MEMORY_SCOPE_AGENT);
                if ((unsigned int)(v & 0xFFFFu) == etag &&
                    (unsigned int)((v >> 32) & 0xFFFFu) == etag) break;
            }
            hbuf[HIDX(upair * 2)]     = bfhi((unsigned int)v);
            hbuf[HIDX(upair * 2 + 1)] = bfhi((unsigned int)(v >> 32));
        }
        __syncthreads();
    }
}

// ---------------- GAT helpers ----------------
__global__ void gat_scores(const float* __restrict__ Wh, const float* __restrict__ a,
                           float* __restrict__ s1, float* __restrict__ s2) {
    int i = blockIdx.x;
    int lane = threadIdx.x;  // 64
    const float* rowp = Wh + (size_t)i * HCAT;
    float p1 = 0.f, p2 = 0.f;
    for (int k = lane; k < HCAT; k += 64) {
        float w = rowp[k];
        p1 += w * a[k];
        p2 += w * a[HCAT + k];
    }
    for (int off = 32; off; off >>= 1) {
        p1 += __shfl_down(p1, off, 64);
        p2 += __shfl_down(p2, off, 64);
    }
    if (lane == 0) { s1[i] = p1; s2[i] = p2; }
}

__global__ void reduce_max_k(const float* __restrict__ s2, float* __restrict__ outv) {
    __shared__ float red[256];
    int tid = threadIdx.x;
    float m = -INFINITY;
    for (int k = tid; k < SEQL; k += 256) m = fmaxf(m, s2[k]);
    red[tid] = m;
    __syncthreads();
    for (int off = 128; off; off >>= 1) {
        if (tid < off) red[tid] = fmaxf(red[tid], red[tid + off]);
        __syncthreads();
    }
    if (tid == 0) outv[0] = red[0];
}

__global__ void gat_p(const float* __restrict__ s1, const float* __restrict__ s2,
                      const float* __restrict__ s2m, float* __restrict__ P,
                      float* __restrict__ Z) {
    int i = blockIdx.x;
    int tid = threadIdx.x;  // 256
    float base = s1[i];
    float m = base + s2m[0];
    m = m > 0.f ? m : ALPHA_LR * m;  // leaky_relu monotonic -> exact row max
    float zs = 0.f;
    for (int jj = tid; jj < SEQL; jj += 256) {
        float e = base + s2[jj];
        e = e > 0.f ? e : ALPHA_LR * e;
        float p = __expf(e - m);
        P[(size_t)i * SEQL + jj] = p;
        zs += p;
    }
    __shared__ float red[256];
    red[tid] = zs;
    __syncthreads();
    for (int off = 128; off; off >>= 1) {
        if (tid < off) red[tid] += red[tid + off];
        __syncthreads();
    }
    if (tid == 0) Z[i] = red[0];
}

// ---------------- Viterbi (max-plus parallel scan) ----------------
__global__ void vit_chunkA(const float* __restrict__ feats, const float* __restrict__ trans,
                           float* __restrict__ chunkA) {
    int c = blockIdx.x;
    int tid = threadIdx.x;  // 128
    __shared__ float Acur[121], tr[121];
    if (tid < 121) tr[tid] = trans[tid];
    __syncthreads();
    int n = tid / 11, p = tid % 11;
    int t0 = c * VCS;
    if (tid < 121) Acur[tid] = tr[tid] + feats[t0 * TT + n];
    __syncthreads();
    for (int t = t0 + 1; t < t0 + VCS; ++t) {
        float v = -INFINITY;
        if (tid < 121) {
            float ft = feats[t * TT + n];
#pragma unroll
            for (int k = 0; k < 11; ++k) v = fmaxf(v, tr[n * 11 + k] + Acur[k * 11 + p]);
            v += ft;
        }
        __syncthreads();
        if (tid < 121) Acur[tid] = v;
        __syncthreads();
    }
    if (tid < 121) chunkA[c * 121 + tid] = Acur[tid];
}

__global__ void vit_prefix(const float* __restrict__ chunkA, float* __restrict__ fvstart) {
    int tid = threadIdx.x;  // 128
    __shared__ float fv[11];
    if (tid < 11) fv[tid] = (tid == START_TAG) ? 0.f : NEGV;
    __syncthreads();
    if (tid < 11) fvstart[tid] = fv[tid];
    for (int c = 0; c < VCH; ++c) {
        float v = -INFINITY;
        if (tid < 11) {
            for (int p = 0; p < 11; ++p) v = fmaxf(v, chunkA[c * 121 + tid * 11 + p] + fv[p]);
        }
        __syncthreads();
        if (tid < 11) { fv[tid] = v; fvstart[(c + 1) * TT + tid] = v; }
        __syncthreads();
    }
}

__global__ void vit_chunkC(const float* __restrict__ feats, const float* __restrict__ trans,
                           const float* __restrict__ fvstart, int* __restrict__ bp,
                           float* __restrict__ fvfinal) {
    int c = blockIdx.x;
    int tid = threadIdx.x;  // 128
    __shared__ float fv[11], tr[121], sc[121], mx[11];
    if (tid < 121) tr[tid] = trans[tid];
    if (tid < 11) fv[tid] = fvstart[c * TT + tid];
    __syncthreads();
    int t0 = c * VCS;
    for (int t = t0; t < t0 + VCS; ++t) {
        if (tid < 121) sc[tid] = fv[tid % 11] + tr[tid];
        __syncthreads();
        if (tid < 11) {
            float best = -INFINITY;
            int bi = 0;
            for (int k = 0; k < 11; ++k) {
                float v = sc[tid * 11 + k];
                if (v > best) { best = v; bi = k; }
            }
            bp[t * TT + tid] = bi;
            mx[tid] = best + feats[t * TT + tid];
        }
        __syncthreads();
        if (tid < 11) fv[tid] = mx[tid];
        __syncthreads();
    }
    if (c == VCH - 1 && tid < 11) fvfinal[tid] = fv[tid];
}

__global__ __launch_bounds__(1024) void vit_back(const int* __restrict__ bp,
                                                 const float* __restrict__ fvfinal,
                                                 const float* __restrict__ trans,
                                                 float* __restrict__ outp) {
    __shared__ unsigned char bufA[SEQL * TT];
    __shared__ unsigned char bufB[SEQL * TT];
    __shared__ int bestIdx;
    int tid = threadIdx.x;
    for (int idx = tid; idx < SEQL * TT; idx += 1024) {
        int t = idx / TT, n = idx - t * TT;
        bufA[idx] = (t < SEQL - 1) ? (unsigned char)bp[(t + 1) * TT + n] : (unsigned char)n;
    }
    __syncthreads();
    unsigned char* a = bufA;
    unsigned char* b = bufB;
    for (int len = 1; len < SEQL - 1; len <<= 1) {
        for (int idx = tid; idx < SEQL * TT; idx += 1024) {
            int t = idx / TT, n = idx - t * TT;
            int m = (t + len <= SEQL - 1) ? (int)a[(t + len) * TT + n] : n;
            b[t * TT + n] = a[t * TT + m];
        }
        __syncthreads();
        unsigned char* tmp = a; a = b; b = tmp;
        __syncthreads();
    }
    if (tid == 0) {
        float bs = -INFINITY;
        int bi = 0;
        for (int p = 0; p < 11; ++p) {
            float v = fvfinal[p] + trans[STOP_TAG * 11 + p];
            if (v > bs) { bs = v; bi = p; }
        }
        outp[0] = bs;
        bestIdx = bi;
    }
    __syncthreads();
    int best = bestIdx;
    for (int t = tid; t < SEQL; t += 1024) outp[1 + t] = (float)a[t * TT + best];
}

// ---------------- host launcher ----------------
extern "C" void kernel_launch(void* const* d_in, const int* in_sizes, int n_in,
                              void* d_out, int out_size, void* d_ws, size_t ws_size,
                              hipStream_t stream) {
    const int* sent = (const int*)d_in[0];
    const float* emb = (const float*)d_in[1];
    const float* w1f = (const float*)d_in[2];
    const float* u1f = (const float*)d_in[3];
    const float* b1f = (const float*)d_in[4];
    const float* w1b = (const float*)d_in[5];
    const float* u1b = (const float*)d_in[6];
    const float* b1b = (const float*)d_in[7];
    const float* hc1 = (const float*)d_in[8];
    const float* g1W = (const float*)d_in[9];
    const float* g1a = (const float*)d_in[10];
    const float* g2W = (const float*)d_in[11];
    const float* g2a = (const float*)d_in[12];
    const float* w2f = (const float*)d_in[13];
    const float* u2f = (const float*)d_in[14];
    const float* b2f = (const float*)d_in[15];
    const float* w2b = (const float*)d_in[16];
    const float* u2b = (const float*)d_in[17];
    const float* b2b = (const float*)d_in[18];
    const float* hc2 = (const float*)d_in[19];
    const float* wtag = (const float*)d_in[20];
    const float* btag = (const float*)d_in[21];
    const float* trans = (const float*)d_in[22];

    float* ws = (float*)d_ws;
    float* x = ws;                      // 524288
    float* R1 = x + 524288;             // 4194304 floats (xin_f+xin_b | P)
    float* xin_f = R1;
    float* xin_b = R1 + 2097152;
    float* P = R1;
    float* h1cat = R1 + 4194304;        // 1048576 (h1cat | g2)
    float* Wh = h1cat + 1048576;        // 1048576
    float* g1 = Wh + 1048576;           // 1048576 (g1 | h2cat)
    float* s1 = g1 + 1048576;           // 2048
    float* s2 = s1 + 2048;              // 2048
    float* Zr = s2 + 2048;              // 2048
    float* s2m = Zr + 2048;             // 16
    unsigned int* pub = (unsigned int*)(s2m + 16);  // 1024 u32 (8B-aligned)
    float* feats = (float*)(pub + 1024);            // 22528
    float* chA = feats + 22528;         // 7744
    float* fvst = chA + 7744;           // 720
    float* fvfin = fvst + 720;          // 16
    int* bp = (int*)(fvfin + 16);       // 22528 ints
    float* Cpart = (float*)(bp + 22528); // 4x1048576 floats (16MB)

    hipMemsetAsync(pub, 0, 1024 * sizeof(unsigned int), stream);

    embed_k<<<SEQL, 256, 0, stream>>>(sent, emb, x);

    // BiLSTM 1 input projections
    gemm_nt<<<dim3(16, 32), 256, 0, stream>>>(x, w1f, b1f, xin_f, SEQL, G4, EDIM);
    gemm_nt<<<dim3(16, 32), 256, 0, stream>>>(x, w1b, b1b, xin_b, SEQL, G4, EDIM);
    lstm_lds<<<128, 256, 0, stream>>>(xin_f, xin_b, u1f, u1b, hc1, h1cat, pub, 0);

    // GAT 1 (both GEMMs K-split x4 for occupancy)
    gemm_nn_ks<<<dim3(8, 32, 4), 256, 0, stream>>>(h1cat, g1W, Cpart, SEQL, HCAT, HCAT / 4);
    sum4_fin<<<4096, 256, 0, stream>>>(Cpart, Wh, SEQL * HCAT);
    gat_scores<<<SEQL, 64, 0, stream>>>(Wh, g1a, s1, s2);
    reduce_max_k<<<1, 256, 0, stream>>>(s2, s2m);
    gat_p<<<SEQL, 256, 0, stream>>>(s1, s2, s2m, P, Zr);
    gemm_nn_ks<<<dim3(8, 32, 4), 256, 0, stream>>>(P, Wh, Cpart, SEQL, HCAT, SEQL / 4);
    attn_fin<<<4096, 256, 0, stream>>>(Cpart, Zr, g1, SEQL * HCAT, HCAT);

    // GAT 2
    gemm_nn_ks<<<dim3(8, 32, 4), 256, 0, stream>>>(g1, g2W, Cpart, SEQL, HCAT, HCAT / 4);
    sum4_fin<<<4096, 256, 0, stream>>>(Cpart, Wh, SEQL * HCAT);
    gat_scores<<<SEQL, 64, 0, stream>>>(Wh, g2a, s1, s2);
    reduce_max_k<<<1, 256, 0, stream>>>(s2, s2m);
    gat_p<<<SEQL, 256, 0, stream>>>(s1, s2, s2m, P, Zr);
    float* g2v = h1cat;  // reuse
    gemm_nn_ks<<<dim3(8, 32, 4), 256, 0, stream>>>(P, Wh, Cpart, SEQL, HCAT, SEQL / 4);
    attn_fin<<<4096, 256, 0, stream>>>(Cpart, Zr, g2v, SEQL * HCAT, HCAT);

    // BiLSTM 2
    gemm_nt<<<dim3(16, 32), 256, 0, stream>>>(g2v, w2f, b2f, xin_f, SEQL, G4, HCAT);
    gemm_nt<<<dim3(16, 32), 256, 0, stream>>>(g2v, w2b, b2b, xin_b, SEQL, G4, HCAT);
    float* h2cat = g1;  // reuse
    lstm_lds<<<128, 256, 0, stream>>>(xin_f, xin_b, u2f, u2b, hc2, h2cat, pub, 2048);

    // tag projection + Viterbi
    gemm_nt<<<dim3(1, 32), 256, 0, stream>>>(h2cat, wtag, btag, feats, SEQL, TT, HCAT);
    vit_chunkA<<<VCH, 128, 0, stream>>>(feats, trans, chA);
    vit_prefix<<<1, 128, 0, stream>>>(chA, fvst);
    vit_chunkC<<<VCH, 128, 0, stream>>>(feats, trans, fvst, bp, fvfin);
    vit_back<<<1, 1024, 0, stream>>>(bp, fvfin, trans, (float*)d_out);
}